// Round 1
// baseline (3181.542 us; speedup 1.0000x reference)
//
#include <hip/hip_runtime.h>
#include <math.h>

#define NN 50000
#define NE 300000
#define DIN 768
#define DHID 256
#define DOUT 128
#define H0 8
#define D0 32

// ---------------- GEMM: C[M,Nc] = A[M,K] @ B[K,Nc] + bias ----------------
// BM=BN=64, BK=16, 256 threads, 4x4 per thread. Requires K%16==0, Nc%64==0.
__global__ __launch_bounds__(256) void gemm_bias_kernel(
    const float* __restrict__ A, const float* __restrict__ B,
    const float* __restrict__ bias, float* __restrict__ C,
    int M, int K, int Nc)
{
    __shared__ float As[16][68];   // [k][m]
    __shared__ float Bs[16][68];   // [k][n]
    const int t  = threadIdx.x;
    const int tx = t & 15, ty = t >> 4;
    const int bm = blockIdx.y * 64, bn = blockIdx.x * 64;

    float acc[4][4] = {};
    for (int k0 = 0; k0 < K; k0 += 16) {
        #pragma unroll
        for (int i = 0; i < 4; ++i) {
            int lin = t + i * 256;            // 0..1023
            int r = lin >> 4, kk = lin & 15;  // 64 rows x 16 k
            int row = bm + r;
            As[kk][r] = (row < M) ? A[(size_t)row * K + k0 + kk] : 0.f;
        }
        #pragma unroll
        for (int i = 0; i < 4; ++i) {
            int lin = t + i * 256;
            int kk = lin >> 6, n = lin & 63;  // 16 k x 64 n
            Bs[kk][n] = B[(size_t)(k0 + kk) * Nc + bn + n];
        }
        __syncthreads();
        #pragma unroll
        for (int kk = 0; kk < 16; ++kk) {
            float a0 = As[kk][ty * 4 + 0], a1 = As[kk][ty * 4 + 1];
            float a2 = As[kk][ty * 4 + 2], a3 = As[kk][ty * 4 + 3];
            float b0 = Bs[kk][tx * 4 + 0], b1 = Bs[kk][tx * 4 + 1];
            float b2 = Bs[kk][tx * 4 + 2], b3 = Bs[kk][tx * 4 + 3];
            acc[0][0] += a0 * b0; acc[0][1] += a0 * b1; acc[0][2] += a0 * b2; acc[0][3] += a0 * b3;
            acc[1][0] += a1 * b0; acc[1][1] += a1 * b1; acc[1][2] += a1 * b2; acc[1][3] += a1 * b3;
            acc[2][0] += a2 * b0; acc[2][1] += a2 * b1; acc[2][2] += a2 * b2; acc[2][3] += a2 * b3;
            acc[3][0] += a3 * b0; acc[3][1] += a3 * b1; acc[3][2] += a3 * b2; acc[3][3] += a3 * b3;
        }
        __syncthreads();
    }
    #pragma unroll
    for (int i = 0; i < 4; ++i) {
        int row = bm + ty * 4 + i;
        if (row >= M) continue;
        #pragma unroll
        for (int j = 0; j < 4; ++j) {
            int col = bn + tx * 4 + j;
            C[(size_t)row * Nc + col] = acc[i][j] + bias[col];
        }
    }
}

// ---------------- per-node attention score dots: s[n,h] = sum_d x[n,h*D+d]*a[h,d] ----------------
__global__ void node_scores_kernel(const float* __restrict__ x, const float* __restrict__ a,
                                   float* __restrict__ s, int n, int H, int D)
{
    int gid = blockIdx.x * blockDim.x + threadIdx.x;
    if (gid >= n * H) return;
    int node = gid / H, h = gid - node * H;
    const float* xr = x + (size_t)node * H * D + h * D;
    const float* ar = a + h * D;
    float acc = 0.f;
    for (int d = 0; d < D; d += 4) {
        float4 xv = *(const float4*)(xr + d);
        float4 av = *(const float4*)(ar + d);
        acc += xv.x * av.x + xv.y * av.y + xv.z * av.z + xv.w * av.w;
    }
    s[gid] = acc;
}

// monotone float<->uint key for atomic max
__device__ __forceinline__ unsigned fkey(float f) {
    unsigned u = __float_as_uint(f);
    return (u & 0x80000000u) ? ~u : (u | 0x80000000u);
}
__device__ __forceinline__ float funkey(unsigned k) {
    unsigned u = (k & 0x80000000u) ? (k & 0x7fffffffu) : ~k;
    return __uint_as_float(u);
}

// al = leaky_relu(ssrc[src]+sdst[dst]); store al; segment max via atomicMax
__global__ void edge_max_kernel(const int* __restrict__ src, const int* __restrict__ dst,
                                const float* __restrict__ ssrc, const float* __restrict__ sdst,
                                float* __restrict__ al, unsigned* __restrict__ amax,
                                int E, int H)
{
    int gid = blockIdx.x * blockDim.x + threadIdx.x;
    if (gid >= E * H) return;
    int e = gid / H, h = gid - e * H;
    int s = src[e], d = dst[e];
    float v = ssrc[s * H + h] + sdst[d * H + h];
    v = (v >= 0.f) ? v : 0.2f * v;
    al[gid] = v;
    atomicMax(&amax[d * H + h], fkey(v));
}

// ex = exp(al - amax[dst]); store over al; denom += ex
__global__ void edge_exp_kernel(const int* __restrict__ dst, float* __restrict__ al,
                                const unsigned* __restrict__ amax, float* __restrict__ denom,
                                int E, int H)
{
    int gid = blockIdx.x * blockDim.x + threadIdx.x;
    if (gid >= E * H) return;
    int e = gid / H, h = gid - e * H;
    int d = dst[e];
    float m = funkey(amax[d * H + h]);
    float ex = expf(al[gid] - m);
    al[gid] = ex;
    atomicAdd(&denom[d * H + h], ex);
}

// agg[dst, c] += xsrc[src, c] * ex / (denom[dst,h] + 1e-16)
__global__ void edge_scatter_kernel(const int* __restrict__ src, const int* __restrict__ dst,
                                    const float* __restrict__ x, const float* __restrict__ ex,
                                    const float* __restrict__ denom, float* __restrict__ agg,
                                    int E, int H, int D)
{
    int C = H * D;
    long long gid = (long long)blockIdx.x * blockDim.x + threadIdx.x;
    if (gid >= (long long)E * C) return;
    int e = (int)(gid / C), c = (int)(gid - (long long)e * C);
    int h = c / D;
    int s = src[e], d = dst[e];
    float alpha = ex[e * H + h] / (denom[d * H + h] + 1e-16f);
    atomicAdd(&agg[(size_t)d * C + c], x[(size_t)s * C + c] * alpha);
}

// partial[c] += sum_{rows of this block} tanh( relu(x_row) @ Wk + bk )[c]
// blockDim.x == C (<=256); 16 rows per block; n % 16 == 0 assumed (50000 = 3125*16)
__global__ void sem_tanh_mean_kernel(const float* __restrict__ x, const float* __restrict__ Wk,
                                     const float* __restrict__ bk, float* __restrict__ partial,
                                     int n, int C)
{
    __shared__ float rows[16][256];
    int c = threadIdx.x;
    int r0 = blockIdx.x * 16;
    for (int r = 0; r < 16; ++r)
        rows[r][c] = fmaxf(x[(size_t)(r0 + r) * C + c], 0.f);
    __syncthreads();
    float acc[16];
    float b = bk[c];
    #pragma unroll
    for (int r = 0; r < 16; ++r) acc[r] = b;
    for (int k = 0; k < C; ++k) {
        float w = Wk[(size_t)k * C + c];
        #pragma unroll
        for (int r = 0; r < 16; ++r) acc[r] += rows[r][k] * w;
    }
    float s = 0.f;
    #pragma unroll
    for (int r = 0; r < 16; ++r) s += tanhf(acc[r]);
    atomicAdd(&partial[c], s);
}

// score_m = sum_c q[c]*partial[m][c]/n ; w = softmax over m=0,1
__global__ void sem_weights_kernel(const float* __restrict__ partial, const float* __restrict__ q,
                                   float* __restrict__ w, int C, int n)
{
    if (threadIdx.x != 0 || blockIdx.x != 0) return;
    float inv = 1.f / (float)n;
    float s0 = 0.f, s1 = 0.f;
    for (int c = 0; c < C; ++c) {
        s0 += q[c] * partial[c] * inv;
        s1 += q[c] * partial[C + c] * inv;
    }
    float m = fmaxf(s0, s1);
    float e0 = expf(s0 - m), e1 = expf(s1 - m);
    float den = e0 + e1;
    w[0] = e0 / den;
    w[1] = e1 / den;
}

// out = w0*relu(a) + w1*relu(b)   (ELU skipped: result is provably >= 0)
__global__ void combine2_kernel(const float* __restrict__ a, const float* __restrict__ b,
                                const float* __restrict__ w, float* __restrict__ out, long long n)
{
    long long gid = (long long)blockIdx.x * blockDim.x + threadIdx.x;
    if (gid >= n) return;
    out[gid] = w[0] * fmaxf(a[gid], 0.f) + w[1] * fmaxf(b[gid], 0.f);
}

__global__ void relu_copy_kernel(const float* __restrict__ a, float* __restrict__ out, long long n)
{
    long long gid = (long long)blockIdx.x * blockDim.x + threadIdx.x;
    if (gid >= n) return;
    out[gid] = fmaxf(a[gid], 0.f);
}

// final: paper rows [0,NN): w0*relu(aggW)+w1*relu(aggC); author rows [NN,2NN): relu(aggB); then row L2 norm
__global__ __launch_bounds__(128) void final_norm_kernel(
    const float* __restrict__ aggW, const float* __restrict__ aggC,
    const float* __restrict__ aggB, const float* __restrict__ w,
    float* __restrict__ out)
{
    __shared__ float red[128];
    int row = blockIdx.x;
    int c = threadIdx.x;
    float v;
    if (row < NN) {
        size_t i = (size_t)row * DOUT + c;
        v = w[0] * fmaxf(aggW[i], 0.f) + w[1] * fmaxf(aggC[i], 0.f);
    } else {
        size_t i = (size_t)(row - NN) * DOUT + c;
        v = fmaxf(aggB[i], 0.f);
    }
    red[c] = v * v;
    __syncthreads();
    for (int s = 64; s > 0; s >>= 1) {
        if (c < s) red[c] += red[c + s];
        __syncthreads();
    }
    float norm = sqrtf(red[0]);
    out[(size_t)row * DOUT + c] = v / fmaxf(norm, 1e-12f);
}

// ------------------------------------------------------------------
static void process_rel(const float* xsrc, const float* xdst,
                        const float* a_s, const float* a_d,
                        const int* ei, int H, int D,
                        float* agg, float* escr, float* ssrc, float* sdst,
                        unsigned* amax, float* denom, hipStream_t stream)
{
    const int* src = ei;
    const int* dst = ei + NE;
    const int C = H * D;
    hipMemsetAsync(amax, 0, (size_t)NN * H * sizeof(unsigned), stream);
    hipMemsetAsync(denom, 0, (size_t)NN * H * sizeof(float), stream);
    int nt = NN * H;
    node_scores_kernel<<<(nt + 255) / 256, 256, 0, stream>>>(xsrc, a_s, ssrc, NN, H, D);
    node_scores_kernel<<<(nt + 255) / 256, 256, 0, stream>>>(xdst, a_d, sdst, NN, H, D);
    int et = NE * H;
    edge_max_kernel<<<(et + 255) / 256, 256, 0, stream>>>(src, dst, ssrc, sdst, escr, amax, NE, H);
    edge_exp_kernel<<<(et + 255) / 256, 256, 0, stream>>>(dst, escr, amax, denom, NE, H);
    long long total = (long long)NE * C;
    edge_scatter_kernel<<<(int)((total + 255) / 256), 256, 0, stream>>>(src, dst, xsrc, escr, denom, agg, NE, H, D);
}

extern "C" void kernel_launch(void* const* d_in, const int* in_sizes, int n_in,
                              void* d_out, int out_size, void* d_ws, size_t ws_size,
                              hipStream_t stream)
{
    // input order per setup_inputs()
    const float* x_paper   = (const float*)d_in[0];
    const float* x_author  = (const float*)d_in[1];
    const int*   ei_writes = (const int*)d_in[2];
    const int*   ei_wb     = (const int*)d_in[3];
    const int*   ei_cites  = (const int*)d_in[4];
    const float* W0p = (const float*)d_in[5];  const float* b0p = (const float*)d_in[6];
    const float* W0a = (const float*)d_in[7];  const float* b0a = (const float*)d_in[8];
    const float* a0s_w  = (const float*)d_in[9];  const float* a0d_w  = (const float*)d_in[10];
    const float* a0s_wb = (const float*)d_in[11]; const float* a0d_wb = (const float*)d_in[12];
    const float* a0s_c  = (const float*)d_in[13]; const float* a0d_c  = (const float*)d_in[14];
    const float* Wk0 = (const float*)d_in[15]; const float* bk0 = (const float*)d_in[16];
    const float* q0  = (const float*)d_in[17];
    const float* W1p = (const float*)d_in[18]; const float* b1p = (const float*)d_in[19];
    const float* W1a = (const float*)d_in[20]; const float* b1a = (const float*)d_in[21];
    const float* a1s_w  = (const float*)d_in[22]; const float* a1d_w  = (const float*)d_in[23];
    const float* a1s_wb = (const float*)d_in[24]; const float* a1d_wb = (const float*)d_in[25];
    const float* a1s_c  = (const float*)d_in[26]; const float* a1d_c  = (const float*)d_in[27];
    const float* Wk1 = (const float*)d_in[28]; const float* bk1 = (const float*)d_in[29];
    const float* q1  = (const float*)d_in[30];

    float* out = (float*)d_out;

    // ---- workspace layout (floats) ----
    float* w    = (float*)d_ws;
    float* xhP  = w;                                  // N*256
    float* xhA  = xhP + (size_t)NN * DHID;            // N*256
    float* aggW = xhA + (size_t)NN * DHID;            // N*256
    float* aggC = aggW + (size_t)NN * DHID;           // N*256
    float* aggB = aggC + (size_t)NN * DHID;           // N*256
    float* escr = aggB + (size_t)NN * DHID;           // E*8
    float* ssrc = escr + (size_t)NE * H0;             // N*8
    float* sdst = ssrc + (size_t)NN * H0;             // N*8
    unsigned* amax = (unsigned*)(sdst + (size_t)NN * H0); // N*8
    float* denom = (float*)amax + (size_t)NN * H0;    // N*8
    float* tsum  = denom + (size_t)NN * H0;           // 512
    float* wsem  = tsum + 512;                        // 2

    // layer-1 aliases (over dead layer-0 buffers)
    float* x1P   = aggW;
    float* x1A   = aggC;
    float* agg1W = aggB;
    float* agg1C = aggB + (size_t)NN * DOUT;
    float* agg1B = xhP;

    // ================= layer 0 =================
    hipMemsetAsync(aggW, 0, 3 * (size_t)NN * DHID * sizeof(float), stream); // aggW,aggC,aggB
    hipMemsetAsync(tsum, 0, 512 * sizeof(float), stream);

    dim3 g0(DHID / 64, (NN + 63) / 64);
    gemm_bias_kernel<<<g0, 256, 0, stream>>>(x_paper,  W0p, b0p, xhP, NN, DIN, DHID);
    gemm_bias_kernel<<<g0, 256, 0, stream>>>(x_author, W0a, b0a, xhA, NN, DIN, DHID);

    // writes: author -> paper ; written_by: paper -> author ; cites: paper -> paper
    process_rel(xhA, xhP, a0s_w,  a0d_w,  ei_writes, H0, D0, aggW, escr, ssrc, sdst, amax, denom, stream);
    process_rel(xhP, xhA, a0s_wb, a0d_wb, ei_wb,     H0, D0, aggB, escr, ssrc, sdst, amax, denom, stream);
    process_rel(xhP, xhP, a0s_c,  a0d_c,  ei_cites,  H0, D0, aggC, escr, ssrc, sdst, amax, denom, stream);

    // semantic attention (paper only: M=2; author M=1 -> identity)
    sem_tanh_mean_kernel<<<NN / 16, DHID, 0, stream>>>(aggW, Wk0, bk0, tsum,        NN, DHID);
    sem_tanh_mean_kernel<<<NN / 16, DHID, 0, stream>>>(aggC, Wk0, bk0, tsum + DHID, NN, DHID);
    sem_weights_kernel<<<1, 64, 0, stream>>>(tsum, q0, wsem, DHID, NN);

    long long nel0 = (long long)NN * DHID;
    combine2_kernel<<<(int)((nel0 + 255) / 256), 256, 0, stream>>>(aggW, aggC, wsem, xhP, nel0); // h_paper
    relu_copy_kernel<<<(int)((nel0 + 255) / 256), 256, 0, stream>>>(aggB, xhA, nel0);            // h_author

    // ================= layer 1 =================
    dim3 g1(DOUT / 64, (NN + 63) / 64);
    gemm_bias_kernel<<<g1, 256, 0, stream>>>(xhP, W1p, b1p, x1P, NN, DHID, DOUT);
    gemm_bias_kernel<<<g1, 256, 0, stream>>>(xhA, W1a, b1a, x1A, NN, DHID, DOUT);

    hipMemsetAsync(agg1W, 0, 2 * (size_t)NN * DOUT * sizeof(float), stream); // agg1W + agg1C
    hipMemsetAsync(agg1B, 0, (size_t)NN * DOUT * sizeof(float), stream);
    hipMemsetAsync(tsum, 0, 2 * DOUT * sizeof(float), stream);

    process_rel(x1A, x1P, a1s_w,  a1d_w,  ei_writes, 1, DOUT, agg1W, escr, ssrc, sdst, amax, denom, stream);
    process_rel(x1P, x1A, a1s_wb, a1d_wb, ei_wb,     1, DOUT, agg1B, escr, ssrc, sdst, amax, denom, stream);
    process_rel(x1P, x1P, a1s_c,  a1d_c,  ei_cites,  1, DOUT, agg1C, escr, ssrc, sdst, amax, denom, stream);

    sem_tanh_mean_kernel<<<NN / 16, DOUT, 0, stream>>>(agg1W, Wk1, bk1, tsum,        NN, DOUT);
    sem_tanh_mean_kernel<<<NN / 16, DOUT, 0, stream>>>(agg1C, Wk1, bk1, tsum + DOUT, NN, DOUT);
    sem_weights_kernel<<<1, 64, 0, stream>>>(tsum, q1, wsem, DOUT, NN);

    final_norm_kernel<<<2 * NN, 128, 0, stream>>>(agg1W, agg1C, agg1B, wsem, out);
}